// Round 5
// baseline (142.463 us; speedup 1.0000x reference)
//
#include <hip/hip_runtime.h>
#include <math.h>

// B=16384, D=1024, E=8, T=4, H=512. Output [T,B] f32.
// ws layout: [0,65536) floats  Wcomb f32 [d][64] (cols 0-31 gates t*8+e, 32-63 scores)
//            [65536,65568)     cbias[t*8+e]
//            bytes 262272+     Wfrag: 32 ksteps x {hi,lo}x{nf0..3} x 64 lanes x 8 bf16 (256 KB)

typedef float  f32x4  __attribute__((ext_vector_type(4)));
typedef short  bf16x8 __attribute__((ext_vector_type(8)));

#define WFRAG_OFF_BYTES 262272

// slow-but-rare RNE split (used in precompute/swizzle only)
__device__ __forceinline__ void cvt_pair(float f0, float f1, unsigned int& hi, unsigned int& lo) {
  unsigned int u0 = __float_as_uint(f0), u1 = __float_as_uint(f1);
  unsigned int r0 = u0 + 0x7FFFu + ((u0 >> 16) & 1u);
  unsigned int r1 = u1 + 0x7FFFu + ((u1 >> 16) & 1u);
  float h0 = __uint_as_float(r0 & 0xFFFF0000u);
  float h1 = __uint_as_float(r1 & 0xFFFF0000u);
  hi = (r0 >> 16) | (r1 & 0xFFFF0000u);
  float l0 = f0 - h0, l1 = f1 - h1;
  unsigned int s0 = __float_as_uint(l0), s1 = __float_as_uint(l1);
  unsigned int q0 = s0 + 0x7FFFu + ((s0 >> 16) & 1u);
  unsigned int q1 = s1 + 0x7FFFu + ((s1 >> 16) & 1u);
  lo = (q0 >> 16) | (q1 & 0xFFFF0000u);
}

// fast in-loop split: 1 cvt_pk + unpack + 2 sub + 1 cvt_pk = 6 VALU ops/pair
__device__ __forceinline__ unsigned int cvtpk_bf16(float a, float b) {
  unsigned int r;
  asm("v_cvt_pk_bf16_f32 %0, %1, %2" : "=v"(r) : "v"(a), "v"(b));
  return r;
}
__device__ __forceinline__ void cvt_pair_fast(float f0, float f1, unsigned int& hi, unsigned int& lo) {
  unsigned int h = cvtpk_bf16(f0, f1);                 // low16 = bf16(f0), high16 = bf16(f1)
  float h0 = __uint_as_float(h << 16);
  float h1 = __uint_as_float(h & 0xFFFF0000u);
  lo = cvtpk_bf16(f0 - h0, f1 - h1);
  hi = h;
}

// ---------------- Precompute Wcomb f32 + cbias (verified R1/R2) ----------------
__global__ __launch_bounds__(256) void mmoe_precompute(
    const float* __restrict__ We, const float* __restrict__ be,
    const float* __restrict__ Wg, const float* __restrict__ Wt,
    float* __restrict__ ws)
{
  float* Wcomb = ws;
  float* cbias = ws + 65536;
  const int tid = threadIdx.x, lane = tid & 63, w = tid >> 6;
  const int pairid = blockIdx.x * 4 + w;
  const int e = pairid >> 10, d = pairid & 1023;

  const float* werow = We + (size_t)pairid * 512;
  float a0 = 0.f, a1 = 0.f, a2 = 0.f, a3 = 0.f;
#pragma unroll
  for (int j = 0; j < 8; ++j) {
    int h = lane + j * 64;
    float wv = werow[h];
    a0 = fmaf(wv, Wt[h],        a0);
    a1 = fmaf(wv, Wt[512 + h],  a1);
    a2 = fmaf(wv, Wt[1024 + h], a2);
    a3 = fmaf(wv, Wt[1536 + h], a3);
  }
#pragma unroll
  for (int m = 1; m < 64; m <<= 1) {
    a0 += __shfl_xor(a0, m, 64); a1 += __shfl_xor(a1, m, 64);
    a2 += __shfl_xor(a2, m, 64); a3 += __shfl_xor(a3, m, 64);
  }
  if (lane == 0) {
    Wcomb[d * 64 + 32 + 0 * 8 + e] = a0;
    Wcomb[d * 64 + 32 + 1 * 8 + e] = a1;
    Wcomb[d * 64 + 32 + 2 * 8 + e] = a2;
    Wcomb[d * 64 + 32 + 3 * 8 + e] = a3;
  }
  if (e == 0 && lane < 32) {
    int t = lane >> 3, ee = lane & 7;
    Wcomb[d * 64 + t * 8 + ee] = Wg[t * 8192 + d * 8 + ee];
  }
  if (d == 0) {
    float b0 = 0.f, b1 = 0.f, b2 = 0.f, b3 = 0.f;
#pragma unroll
    for (int j = 0; j < 8; ++j) {
      int h = lane + j * 64;
      float bv = be[e * 512 + h];
      b0 = fmaf(bv, Wt[h],        b0);
      b1 = fmaf(bv, Wt[512 + h],  b1);
      b2 = fmaf(bv, Wt[1024 + h], b2);
      b3 = fmaf(bv, Wt[1536 + h], b3);
    }
#pragma unroll
    for (int m = 1; m < 64; m <<= 1) {
      b0 += __shfl_xor(b0, m, 64); b1 += __shfl_xor(b1, m, 64);
      b2 += __shfl_xor(b2, m, 64); b3 += __shfl_xor(b3, m, 64);
    }
    if (lane == 0) {
      cbias[0 * 8 + e] = b0; cbias[1 * 8 + e] = b1;
      cbias[2 * 8 + e] = b2; cbias[3 * 8 + e] = b3;
    }
  }
}

// ---------------- Swizzle Wcomb -> bf16 hi/lo MFMA B-fragments (verified R2) ----------------
// Slot idx = ks*512 + vn*64 + lane; vn = v*4+nf (v:0=hi,1=lo). Lane l holds
// B[k = ks*32 + (l>>4)*8 + j][n = nf*16 + (l&15)], j=0..7, packed 2 bf16/u32.
__global__ __launch_bounds__(256) void mmoe_swizzle(const float* __restrict__ Wc,
                                                    uint4* __restrict__ wf)
{
  const int idx = blockIdx.x * 256 + threadIdx.x;  // 0..16383
  const int ks = idx >> 9;
  const int rem = idx & 511;
  const int vn = rem >> 6, l = rem & 63;
  const int v = vn >> 2, nf = vn & 3;
  const int n = nf * 16 + (l & 15);
  const int kbase = ks * 32 + (l >> 4) * 8;
  unsigned int pk[4];
#pragma unroll
  for (int p = 0; p < 4; ++p) {
    float f0 = Wc[(size_t)(kbase + 2 * p) * 64 + n];
    float f1 = Wc[(size_t)(kbase + 2 * p + 1) * 64 + n];
    unsigned int hi, lo;
    cvt_pair(f0, f1, hi, lo);
    pk[p] = v ? lo : hi;
  }
  uint4 val; val.x = pk[0]; val.y = pk[1]; val.z = pk[2]; val.w = pk[3];
  wf[idx] = val;
}

// ---------------- Main: 512 single-wave blocks, 32 rows x 64 cols each ----------------
// Two 16-row A-fragments share every B-fragment load (halves Wfrag traffic vs R2).
union UC { unsigned int u[4]; bf16x8 v; };

template <int S>
__device__ __forceinline__ void mmoe_step(
    const float4* __restrict__ xp0, const float4* __restrict__ xp1,
    const bf16x8* __restrict__ bptr, int l,
    float4 (&xbuf)[4][2][2], bf16x8 (&breg)[2][8], f32x4 (&acc)[2][4])
{
  constexpr int D = S & 3;   // xbuf depth slot
  constexpr int P = S & 1;   // breg parity
  float4 xa0 = xbuf[D][0][0], xa1 = xbuf[D][0][1];
  float4 xb0 = xbuf[D][1][0], xb1 = xbuf[D][1][1];
  if constexpr (S + 4 < 32) {
    xbuf[D][0][0] = xp0[(S + 4) * 8];
    xbuf[D][0][1] = xp0[(S + 4) * 8 + 1];
    xbuf[D][1][0] = xp1[(S + 4) * 8];
    xbuf[D][1][1] = xp1[(S + 4) * 8 + 1];
  }
  UC A0h, A0l, A1h, A1l;
  cvt_pair_fast(xa0.x, xa0.y, A0h.u[0], A0l.u[0]);
  cvt_pair_fast(xa0.z, xa0.w, A0h.u[1], A0l.u[1]);
  cvt_pair_fast(xa1.x, xa1.y, A0h.u[2], A0l.u[2]);
  cvt_pair_fast(xa1.z, xa1.w, A0h.u[3], A0l.u[3]);
  cvt_pair_fast(xb0.x, xb0.y, A1h.u[0], A1l.u[0]);
  cvt_pair_fast(xb0.z, xb0.w, A1h.u[1], A1l.u[1]);
  cvt_pair_fast(xb1.x, xb1.y, A1h.u[2], A1l.u[2]);
  cvt_pair_fast(xb1.z, xb1.w, A1h.u[3], A1l.u[3]);

#pragma unroll
  for (int j = 0; j < 4; ++j) {
    acc[0][j] = __builtin_amdgcn_mfma_f32_16x16x32_bf16(A0h.v, breg[P][j], acc[0][j], 0, 0, 0);
  }
#pragma unroll
  for (int j = 0; j < 4; ++j) {
    acc[1][j] = __builtin_amdgcn_mfma_f32_16x16x32_bf16(A1h.v, breg[P][j], acc[1][j], 0, 0, 0);
  }
#pragma unroll
  for (int j = 0; j < 4; ++j) {
    acc[0][j] = __builtin_amdgcn_mfma_f32_16x16x32_bf16(A0h.v, breg[P][j + 4], acc[0][j], 0, 0, 0);
  }
#pragma unroll
  for (int j = 0; j < 4; ++j) {
    acc[1][j] = __builtin_amdgcn_mfma_f32_16x16x32_bf16(A1h.v, breg[P][j + 4], acc[1][j], 0, 0, 0);
  }
#pragma unroll
  for (int j = 0; j < 4; ++j) {
    acc[0][j] = __builtin_amdgcn_mfma_f32_16x16x32_bf16(A0l.v, breg[P][j], acc[0][j], 0, 0, 0);
  }
#pragma unroll
  for (int j = 0; j < 4; ++j) {
    acc[1][j] = __builtin_amdgcn_mfma_f32_16x16x32_bf16(A1l.v, breg[P][j], acc[1][j], 0, 0, 0);
  }
  if constexpr (S + 2 < 32) {
#pragma unroll
    for (int vn = 0; vn < 8; ++vn)
      breg[P][vn] = bptr[(S + 2) * 512 + vn * 64 + l];
  }
}

__global__ __launch_bounds__(64, 1) void mmoe_main(
    const float* __restrict__ x,
    const float* __restrict__ bgp,   // [4][8]
    const float* __restrict__ btp,   // [4]
    const float* __restrict__ ws,
    float* __restrict__ out)
{
  __shared__ float cmat[2048];   // [32 rows][64 cols]
  const int l   = threadIdx.x;
  const int b0g = blockIdx.x * 32;
  const float* cbias = ws + 65536;
  const bf16x8* __restrict__ bptr =
      (const bf16x8*)((const unsigned char*)ws + WFRAG_OFF_BYTES);

  // frag f covers rows b0g + f*16 + (l&15); lane k-octet = (l>>4)*8
  const float4* __restrict__ xp0 =
      (const float4*)(x + (size_t)(b0g + (l & 15)) * 1024) + (l >> 4) * 2;
  const float4* __restrict__ xp1 = xp0 + 16 * 256;   // +16 rows

  float4 xbuf[4][2][2];     // [depth][frag][vec]
  bf16x8 breg[2][8];
  f32x4  acc[2][4];
#pragma unroll
  for (int f = 0; f < 2; ++f)
#pragma unroll
    for (int nf = 0; nf < 4; ++nf) acc[f][nf] = (f32x4){0.f, 0.f, 0.f, 0.f};

  // prologue: x steps 0..3, B steps 0..1
#pragma unroll
  for (int p = 0; p < 4; ++p) {
    xbuf[p][0][0] = xp0[p * 8]; xbuf[p][0][1] = xp0[p * 8 + 1];
    xbuf[p][1][0] = xp1[p * 8]; xbuf[p][1][1] = xp1[p * 8 + 1];
  }
#pragma unroll
  for (int vn = 0; vn < 8; ++vn) breg[0][vn] = bptr[vn * 64 + l];
#pragma unroll
  for (int vn = 0; vn < 8; ++vn) breg[1][vn] = bptr[512 + vn * 64 + l];

#define MSTEP(S) mmoe_step<S>(xp0, xp1, bptr, l, xbuf, breg, acc);
  MSTEP(0)  MSTEP(1)  MSTEP(2)  MSTEP(3)  MSTEP(4)  MSTEP(5)  MSTEP(6)  MSTEP(7)
  MSTEP(8)  MSTEP(9)  MSTEP(10) MSTEP(11) MSTEP(12) MSTEP(13) MSTEP(14) MSTEP(15)
  MSTEP(16) MSTEP(17) MSTEP(18) MSTEP(19) MSTEP(20) MSTEP(21) MSTEP(22) MSTEP(23)
  MSTEP(24) MSTEP(25) MSTEP(26) MSTEP(27) MSTEP(28) MSTEP(29) MSTEP(30) MSTEP(31)
#undef MSTEP

  // ---- epilogue: C frag (col=lane&15, row=(lane>>4)*4+r) -> LDS -> softmax-mix ----
#pragma unroll
  for (int f = 0; f < 2; ++f)
#pragma unroll
    for (int nf = 0; nf < 4; ++nf)
#pragma unroll
      for (int r = 0; r < 4; ++r)
        cmat[(f * 16 + (l >> 4) * 4 + r) * 64 + nf * 16 + (l & 15)] = acc[f][nf][r];
  __syncthreads();

#pragma unroll
  for (int p = 0; p < 2; ++p) {
    const int idx = p * 64 + l;         // 0..127 = 32 rows x 4 tasks
    const int row = idx >> 2, t = idx & 3;
    const float4 ga = *(const float4*)&cmat[row * 64 + t * 8];
    const float4 gb = *(const float4*)&cmat[row * 64 + t * 8 + 4];
    const float4 sa = *(const float4*)&cmat[row * 64 + 32 + t * 8];
    const float4 sb = *(const float4*)&cmat[row * 64 + 32 + t * 8 + 4];
    float g[8] = {ga.x, ga.y, ga.z, ga.w, gb.x, gb.y, gb.z, gb.w};
    float s[8] = {sa.x, sa.y, sa.z, sa.w, sb.x, sb.y, sb.z, sb.w};
#pragma unroll
    for (int e = 0; e < 8; ++e) {
      g[e] += bgp[t * 8 + e];
      s[e] += cbias[t * 8 + e];
    }
    float m = g[0];
#pragma unroll
    for (int e = 1; e < 8; ++e) m = fmaxf(m, g[e]);
    float Z = 0.f, num = 0.f;
#pragma unroll
    for (int e = 0; e < 8; ++e) {
      float p2 = __expf(g[e] - m);
      Z += p2;
      num = fmaf(p2, s[e], num);
    }
    out[t * 16384 + b0g + row] = num / Z + btp[t];
  }
}

extern "C" void kernel_launch(void* const* d_in, const int* in_sizes, int n_in,
                              void* d_out, int out_size, void* d_ws, size_t ws_size,
                              hipStream_t stream) {
  const float* x  = (const float*)d_in[0];
  const float* We = (const float*)d_in[1];
  const float* be = (const float*)d_in[2];
  const float* Wg = (const float*)d_in[3];
  const float* bg = (const float*)d_in[4];
  const float* Wt = (const float*)d_in[5];
  const float* bt = (const float*)d_in[6];
  float* out = (float*)d_out;
  float* ws  = (float*)d_ws;   // needs 524416 bytes

  uint4* wf = (uint4*)((unsigned char*)d_ws + WFRAG_OFF_BYTES);

  hipLaunchKernelGGL(mmoe_precompute, dim3(2048), dim3(256), 0, stream, We, be, Wg, Wt, ws);
  hipLaunchKernelGGL(mmoe_swizzle,    dim3(64),   dim3(256), 0, stream, ws, wf);
  hipLaunchKernelGGL(mmoe_main,       dim3(512),  dim3(64),  0, stream, x, bg, bt, ws, out);
}

// Round 7
// 124.332 us; speedup vs baseline: 1.1458x; 1.1458x over previous
//
#include <hip/hip_runtime.h>
#include <math.h>

// B=16384, D=1024, E=8, T=4, H=512. Output [T,B] f32.
// ws layout: [0,65536) floats  Wcomb f32 [d][64] (cols 0-31 gates t*8+e, 32-63 scores)
//            [65536,65568)     cbias[t*8+e]
//            bytes 262272+     Wfrag: 32 ksteps x {hi,lo}x{nf0..3} x 64 lanes x 8 bf16 (256 KB)

typedef float  f32x4  __attribute__((ext_vector_type(4)));
typedef short  bf16x8 __attribute__((ext_vector_type(8)));

#define WFRAG_OFF_BYTES 262272

// slow-but-rare RNE split (used in precompute/swizzle only)
__device__ __forceinline__ void cvt_pair(float f0, float f1, unsigned int& hi, unsigned int& lo) {
  unsigned int u0 = __float_as_uint(f0), u1 = __float_as_uint(f1);
  unsigned int r0 = u0 + 0x7FFFu + ((u0 >> 16) & 1u);
  unsigned int r1 = u1 + 0x7FFFu + ((u1 >> 16) & 1u);
  float h0 = __uint_as_float(r0 & 0xFFFF0000u);
  float h1 = __uint_as_float(r1 & 0xFFFF0000u);
  hi = (r0 >> 16) | (r1 & 0xFFFF0000u);
  float l0 = f0 - h0, l1 = f1 - h1;
  unsigned int s0 = __float_as_uint(l0), s1 = __float_as_uint(l1);
  unsigned int q0 = s0 + 0x7FFFu + ((s0 >> 16) & 1u);
  unsigned int q1 = s1 + 0x7FFFu + ((s1 >> 16) & 1u);
  lo = (q0 >> 16) | (q1 & 0xFFFF0000u);
}

// fast in-loop split: 1 cvt_pk + unpack + 2 sub + 1 cvt_pk = 6 VALU ops/pair
__device__ __forceinline__ unsigned int cvtpk_bf16(float a, float b) {
  unsigned int r;
  asm("v_cvt_pk_bf16_f32 %0, %1, %2" : "=v"(r) : "v"(a), "v"(b));
  return r;
}
__device__ __forceinline__ void cvt_pair_fast(float f0, float f1, unsigned int& hi, unsigned int& lo) {
  unsigned int h = cvtpk_bf16(f0, f1);                 // low16 = bf16(f0), high16 = bf16(f1)
  float h0 = __uint_as_float(h << 16);
  float h1 = __uint_as_float(h & 0xFFFF0000u);
  lo = cvtpk_bf16(f0 - h0, f1 - h1);
  hi = h;
}

// ---------------- Precompute Wcomb f32 + cbias (verified R1/R2/R5) ----------------
__global__ __launch_bounds__(256) void mmoe_precompute(
    const float* __restrict__ We, const float* __restrict__ be,
    const float* __restrict__ Wg, const float* __restrict__ Wt,
    float* __restrict__ ws)
{
  float* Wcomb = ws;
  float* cbias = ws + 65536;
  const int tid = threadIdx.x, lane = tid & 63, w = tid >> 6;
  const int pairid = blockIdx.x * 4 + w;
  const int e = pairid >> 10, d = pairid & 1023;

  const float* werow = We + (size_t)pairid * 512;
  float a0 = 0.f, a1 = 0.f, a2 = 0.f, a3 = 0.f;
#pragma unroll
  for (int j = 0; j < 8; ++j) {
    int h = lane + j * 64;
    float wv = werow[h];
    a0 = fmaf(wv, Wt[h],        a0);
    a1 = fmaf(wv, Wt[512 + h],  a1);
    a2 = fmaf(wv, Wt[1024 + h], a2);
    a3 = fmaf(wv, Wt[1536 + h], a3);
  }
#pragma unroll
  for (int m = 1; m < 64; m <<= 1) {
    a0 += __shfl_xor(a0, m, 64); a1 += __shfl_xor(a1, m, 64);
    a2 += __shfl_xor(a2, m, 64); a3 += __shfl_xor(a3, m, 64);
  }
  if (lane == 0) {
    Wcomb[d * 64 + 32 + 0 * 8 + e] = a0;
    Wcomb[d * 64 + 32 + 1 * 8 + e] = a1;
    Wcomb[d * 64 + 32 + 2 * 8 + e] = a2;
    Wcomb[d * 64 + 32 + 3 * 8 + e] = a3;
  }
  if (e == 0 && lane < 32) {
    int t = lane >> 3, ee = lane & 7;
    Wcomb[d * 64 + t * 8 + ee] = Wg[t * 8192 + d * 8 + ee];
  }
  if (d == 0) {
    float b0 = 0.f, b1 = 0.f, b2 = 0.f, b3 = 0.f;
#pragma unroll
    for (int j = 0; j < 8; ++j) {
      int h = lane + j * 64;
      float bv = be[e * 512 + h];
      b0 = fmaf(bv, Wt[h],        b0);
      b1 = fmaf(bv, Wt[512 + h],  b1);
      b2 = fmaf(bv, Wt[1024 + h], b2);
      b3 = fmaf(bv, Wt[1536 + h], b3);
    }
#pragma unroll
    for (int m = 1; m < 64; m <<= 1) {
      b0 += __shfl_xor(b0, m, 64); b1 += __shfl_xor(b1, m, 64);
      b2 += __shfl_xor(b2, m, 64); b3 += __shfl_xor(b3, m, 64);
    }
    if (lane == 0) {
      cbias[0 * 8 + e] = b0; cbias[1 * 8 + e] = b1;
      cbias[2 * 8 + e] = b2; cbias[3 * 8 + e] = b3;
    }
  }
}

// ---------------- Swizzle Wcomb -> bf16 hi/lo MFMA B-fragments (verified R2/R5) ----------------
// Slot idx = ks*512 + vn*64 + lane; vn = v*4+nf (v:0=hi,1=lo). Lane l holds
// B[k = ks*32 + (l>>4)*8 + j][n = nf*16 + (l&15)], j=0..7, packed 2 bf16/u32.
__global__ __launch_bounds__(256) void mmoe_swizzle(const float* __restrict__ Wc,
                                                    uint4* __restrict__ wf)
{
  const int idx = blockIdx.x * 256 + threadIdx.x;  // 0..16383
  const int ks = idx >> 9;
  const int rem = idx & 511;
  const int vn = rem >> 6, l = rem & 63;
  const int v = vn >> 2, nf = vn & 3;
  const int n = nf * 16 + (l & 15);
  const int kbase = ks * 32 + (l >> 4) * 8;
  unsigned int pk[4];
#pragma unroll
  for (int p = 0; p < 4; ++p) {
    float f0 = Wc[(size_t)(kbase + 2 * p) * 64 + n];
    float f1 = Wc[(size_t)(kbase + 2 * p + 1) * 64 + n];
    unsigned int hi, lo;
    cvt_pair(f0, f1, hi, lo);
    pk[p] = v ? lo : hi;
  }
  uint4 val; val.x = pk[0]; val.y = pk[1]; val.z = pk[2]; val.w = pk[3];
  wf[idx] = val;
}

// ---------------- Main: 512 blocks x 4 waves; 32 rows/block, K-split 4 ----------------
// Wave w handles k in [w*256,(w+1)*256) for the block's 32 rows: 8 steps of K=32.
// Partial 32x64 tiles reduced 4-way through LDS, then fused softmax-mix epilogue.
union UC { unsigned int u[4]; bf16x8 v; };

template <int S>
__device__ __forceinline__ void mmoe_step(
    const float4* __restrict__ xp0, const float4* __restrict__ xp1,
    const bf16x8* __restrict__ bptrw, int l,
    float4 (&xbuf)[4][2][2], bf16x8 (&breg)[2][8], f32x4 (&acc)[2][4])
{
  constexpr int D = S & 3;   // xbuf depth slot
  constexpr int P = S & 1;   // breg parity
  float4 xa0 = xbuf[D][0][0], xa1 = xbuf[D][0][1];
  float4 xb0 = xbuf[D][1][0], xb1 = xbuf[D][1][1];
  if constexpr (S + 4 < 8) {
    xbuf[D][0][0] = xp0[(S + 4) * 8];
    xbuf[D][0][1] = xp0[(S + 4) * 8 + 1];
    xbuf[D][1][0] = xp1[(S + 4) * 8];
    xbuf[D][1][1] = xp1[(S + 4) * 8 + 1];
  }
  UC A0h, A0l, A1h, A1l;
  cvt_pair_fast(xa0.x, xa0.y, A0h.u[0], A0l.u[0]);
  cvt_pair_fast(xa0.z, xa0.w, A0h.u[1], A0l.u[1]);
  cvt_pair_fast(xa1.x, xa1.y, A0h.u[2], A0l.u[2]);
  cvt_pair_fast(xa1.z, xa1.w, A0h.u[3], A0l.u[3]);
  cvt_pair_fast(xb0.x, xb0.y, A1h.u[0], A1l.u[0]);
  cvt_pair_fast(xb0.z, xb0.w, A1h.u[1], A1l.u[1]);
  cvt_pair_fast(xb1.x, xb1.y, A1h.u[2], A1l.u[2]);
  cvt_pair_fast(xb1.z, xb1.w, A1h.u[3], A1l.u[3]);

  // bf16x3: Ah*Bh (j 0..3), Ah*Bl (j 4..7 are lo-B frags), Al*Bh
#pragma unroll
  for (int j = 0; j < 4; ++j)
    acc[0][j] = __builtin_amdgcn_mfma_f32_16x16x32_bf16(A0h.v, breg[P][j], acc[0][j], 0, 0, 0);
#pragma unroll
  for (int j = 0; j < 4; ++j)
    acc[1][j] = __builtin_amdgcn_mfma_f32_16x16x32_bf16(A1h.v, breg[P][j], acc[1][j], 0, 0, 0);
#pragma unroll
  for (int j = 0; j < 4; ++j)
    acc[0][j] = __builtin_amdgcn_mfma_f32_16x16x32_bf16(A0h.v, breg[P][j + 4], acc[0][j], 0, 0, 0);
#pragma unroll
  for (int j = 0; j < 4; ++j)
    acc[1][j] = __builtin_amdgcn_mfma_f32_16x16x32_bf16(A1h.v, breg[P][j + 4], acc[1][j], 0, 0, 0);
#pragma unroll
  for (int j = 0; j < 4; ++j)
    acc[0][j] = __builtin_amdgcn_mfma_f32_16x16x32_bf16(A0l.v, breg[P][j], acc[0][j], 0, 0, 0);
#pragma unroll
  for (int j = 0; j < 4; ++j)
    acc[1][j] = __builtin_amdgcn_mfma_f32_16x16x32_bf16(A1l.v, breg[P][j], acc[1][j], 0, 0, 0);
  if constexpr (S + 2 < 8) {
#pragma unroll
    for (int vn = 0; vn < 8; ++vn)
      breg[P][vn] = bptrw[(S + 2) * 512 + vn * 64 + l];
  }
}

__global__ __launch_bounds__(256, 2) void mmoe_main(
    const float* __restrict__ x,
    const float* __restrict__ bgp,   // [4][8]
    const float* __restrict__ btp,   // [4]
    const float* __restrict__ ws,
    float* __restrict__ out)
{
  __shared__ float cmat[4 * 2048];   // [wave][32 rows][64 cols]
  const int tid = threadIdx.x;
  const int l   = tid & 63;
  const int w   = tid >> 6;          // K-quarter 0..3
  const int b0g = blockIdx.x * 32;
  const float* cbias = ws + 65536;
  const bf16x8* __restrict__ bptrw =
      (const bf16x8*)((const unsigned char*)ws + WFRAG_OFF_BYTES) + w * 8 * 512;

  // frag f covers rows b0g + f*16 + (l&15); lane k-octet (l>>4)*8 inside wave's K-quarter
  const float4* __restrict__ xp0 =
      (const float4*)(x + (size_t)(b0g + (l & 15)) * 1024) + w * 64 + (l >> 4) * 2;
  const float4* __restrict__ xp1 = xp0 + 16 * 256;   // +16 rows

  float4 xbuf[4][2][2];     // [depth][frag][vec]
  bf16x8 breg[2][8];
  f32x4  acc[2][4];
#pragma unroll
  for (int f = 0; f < 2; ++f)
#pragma unroll
    for (int nf = 0; nf < 4; ++nf) acc[f][nf] = (f32x4){0.f, 0.f, 0.f, 0.f};

  // prologue: x steps 0..3, B steps 0..1
#pragma unroll
  for (int p = 0; p < 4; ++p) {
    xbuf[p][0][0] = xp0[p * 8]; xbuf[p][0][1] = xp0[p * 8 + 1];
    xbuf[p][1][0] = xp1[p * 8]; xbuf[p][1][1] = xp1[p * 8 + 1];
  }
#pragma unroll
  for (int vn = 0; vn < 8; ++vn) breg[0][vn] = bptrw[vn * 64 + l];
#pragma unroll
  for (int vn = 0; vn < 8; ++vn) breg[1][vn] = bptrw[512 + vn * 64 + l];

  mmoe_step<0>(xp0, xp1, bptrw, l, xbuf, breg, acc);
  mmoe_step<1>(xp0, xp1, bptrw, l, xbuf, breg, acc);
  mmoe_step<2>(xp0, xp1, bptrw, l, xbuf, breg, acc);
  mmoe_step<3>(xp0, xp1, bptrw, l, xbuf, breg, acc);
  mmoe_step<4>(xp0, xp1, bptrw, l, xbuf, breg, acc);
  mmoe_step<5>(xp0, xp1, bptrw, l, xbuf, breg, acc);
  mmoe_step<6>(xp0, xp1, bptrw, l, xbuf, breg, acc);
  mmoe_step<7>(xp0, xp1, bptrw, l, xbuf, breg, acc);

  // ---- write partials: C frag (col=lane&15, row=(lane>>4)*4+r) ----
#pragma unroll
  for (int f = 0; f < 2; ++f)
#pragma unroll
    for (int nf = 0; nf < 4; ++nf)
#pragma unroll
      for (int r = 0; r < 4; ++r)
        cmat[w * 2048 + (f * 16 + (l >> 4) * 4 + r) * 64 + nf * 16 + (l & 15)] = acc[f][nf][r];
  __syncthreads();

  // ---- 4-way reduce + softmax-mix (threads 0..127: 32 rows x 4 tasks) ----
  if (tid < 128) {
    const int row = tid >> 2, t = tid & 3;
    float g[8] = {0.f, 0.f, 0.f, 0.f, 0.f, 0.f, 0.f, 0.f};
    float s[8] = {0.f, 0.f, 0.f, 0.f, 0.f, 0.f, 0.f, 0.f};
#pragma unroll
    for (int wv = 0; wv < 4; ++wv) {
      const float4 ga = *(const float4*)&cmat[wv * 2048 + row * 64 + t * 8];
      const float4 gb = *(const float4*)&cmat[wv * 2048 + row * 64 + t * 8 + 4];
      const float4 sa = *(const float4*)&cmat[wv * 2048 + row * 64 + 32 + t * 8];
      const float4 sb = *(const float4*)&cmat[wv * 2048 + row * 64 + 32 + t * 8 + 4];
      g[0] += ga.x; g[1] += ga.y; g[2] += ga.z; g[3] += ga.w;
      g[4] += gb.x; g[5] += gb.y; g[6] += gb.z; g[7] += gb.w;
      s[0] += sa.x; s[1] += sa.y; s[2] += sa.z; s[3] += sa.w;
      s[4] += sb.x; s[5] += sb.y; s[6] += sb.z; s[7] += sb.w;
    }
#pragma unroll
    for (int e = 0; e < 8; ++e) {
      g[e] += bgp[t * 8 + e];
      s[e] += cbias[t * 8 + e];
    }
    float m = g[0];
#pragma unroll
    for (int e = 1; e < 8; ++e) m = fmaxf(m, g[e]);
    float Z = 0.f, num = 0.f;
#pragma unroll
    for (int e = 0; e < 8; ++e) {
      float p2 = __expf(g[e] - m);
      Z += p2;
      num = fmaf(p2, s[e], num);
    }
    out[t * 16384 + b0g + row] = num / Z + btp[t];
  }
}

extern "C" void kernel_launch(void* const* d_in, const int* in_sizes, int n_in,
                              void* d_out, int out_size, void* d_ws, size_t ws_size,
                              hipStream_t stream) {
  const float* x  = (const float*)d_in[0];
  const float* We = (const float*)d_in[1];
  const float* be = (const float*)d_in[2];
  const float* Wg = (const float*)d_in[3];
  const float* bg = (const float*)d_in[4];
  const float* Wt = (const float*)d_in[5];
  const float* bt = (const float*)d_in[6];
  float* out = (float*)d_out;
  float* ws  = (float*)d_ws;   // needs 524416 bytes

  uint4* wf = (uint4*)((unsigned char*)d_ws + WFRAG_OFF_BYTES);

  hipLaunchKernelGGL(mmoe_precompute, dim3(2048), dim3(256), 0, stream, We, be, Wg, Wt, ws);
  hipLaunchKernelGGL(mmoe_swizzle,    dim3(64),   dim3(256), 0, stream, ws, wf);
  hipLaunchKernelGGL(mmoe_main,       dim3(512),  dim3(256), 0, stream, x, bg, bt, ws, out);
}

// Round 8
// 122.763 us; speedup vs baseline: 1.1605x; 1.0128x over previous
//
#include <hip/hip_runtime.h>
#include <math.h>

// B=16384, D=1024, E=8, T=4, H=512. Output [T,B] f32.
// ws layout: [0,65536) floats  Wcomb f32 [d][64] (cols 0-31 gates t*8+e, 32-63 scores)
//            [65536,65568)     cbias[t*8+e]
//            bytes 262272+     Wfrag: 32 ksteps x {hi,lo}x{nf0..3} x 64 lanes x 8 bf16 (256 KB)

typedef float  f32x4  __attribute__((ext_vector_type(4)));
typedef short  bf16x8 __attribute__((ext_vector_type(8)));

#define WFRAG_OFF_BYTES 262272
#define SCHED_FENCE() __builtin_amdgcn_sched_barrier(0)

// slow-but-rare RNE split (used in precompute/swizzle only)
__device__ __forceinline__ void cvt_pair(float f0, float f1, unsigned int& hi, unsigned int& lo) {
  unsigned int u0 = __float_as_uint(f0), u1 = __float_as_uint(f1);
  unsigned int r0 = u0 + 0x7FFFu + ((u0 >> 16) & 1u);
  unsigned int r1 = u1 + 0x7FFFu + ((u1 >> 16) & 1u);
  float h0 = __uint_as_float(r0 & 0xFFFF0000u);
  float h1 = __uint_as_float(r1 & 0xFFFF0000u);
  hi = (r0 >> 16) | (r1 & 0xFFFF0000u);
  float l0 = f0 - h0, l1 = f1 - h1;
  unsigned int s0 = __float_as_uint(l0), s1 = __float_as_uint(l1);
  unsigned int q0 = s0 + 0x7FFFu + ((s0 >> 16) & 1u);
  unsigned int q1 = s1 + 0x7FFFu + ((s1 >> 16) & 1u);
  lo = (q0 >> 16) | (q1 & 0xFFFF0000u);
}

// fast in-loop split: 1 cvt_pk + unpack + 2 sub + 1 cvt_pk = 6 VALU ops/pair
__device__ __forceinline__ unsigned int cvtpk_bf16(float a, float b) {
  unsigned int r;
  asm("v_cvt_pk_bf16_f32 %0, %1, %2" : "=v"(r) : "v"(a), "v"(b));
  return r;
}
__device__ __forceinline__ void cvt_pair_fast(float f0, float f1, unsigned int& hi, unsigned int& lo) {
  unsigned int h = cvtpk_bf16(f0, f1);                 // low16 = bf16(f0), high16 = bf16(f1)
  float h0 = __uint_as_float(h << 16);
  float h1 = __uint_as_float(h & 0xFFFF0000u);
  lo = cvtpk_bf16(f0 - h0, f1 - h1);
  hi = h;
}

// ---------------- Precompute Wcomb f32 + cbias (verified R1/R2/R5/R7) ----------------
__global__ __launch_bounds__(256) void mmoe_precompute(
    const float* __restrict__ We, const float* __restrict__ be,
    const float* __restrict__ Wg, const float* __restrict__ Wt,
    float* __restrict__ ws)
{
  float* Wcomb = ws;
  float* cbias = ws + 65536;
  const int tid = threadIdx.x, lane = tid & 63, w = tid >> 6;
  const int pairid = blockIdx.x * 4 + w;
  const int e = pairid >> 10, d = pairid & 1023;

  const float* werow = We + (size_t)pairid * 512;
  float a0 = 0.f, a1 = 0.f, a2 = 0.f, a3 = 0.f;
#pragma unroll
  for (int j = 0; j < 8; ++j) {
    int h = lane + j * 64;
    float wv = werow[h];
    a0 = fmaf(wv, Wt[h],        a0);
    a1 = fmaf(wv, Wt[512 + h],  a1);
    a2 = fmaf(wv, Wt[1024 + h], a2);
    a3 = fmaf(wv, Wt[1536 + h], a3);
  }
#pragma unroll
  for (int m = 1; m < 64; m <<= 1) {
    a0 += __shfl_xor(a0, m, 64); a1 += __shfl_xor(a1, m, 64);
    a2 += __shfl_xor(a2, m, 64); a3 += __shfl_xor(a3, m, 64);
  }
  if (lane == 0) {
    Wcomb[d * 64 + 32 + 0 * 8 + e] = a0;
    Wcomb[d * 64 + 32 + 1 * 8 + e] = a1;
    Wcomb[d * 64 + 32 + 2 * 8 + e] = a2;
    Wcomb[d * 64 + 32 + 3 * 8 + e] = a3;
  }
  if (e == 0 && lane < 32) {
    int t = lane >> 3, ee = lane & 7;
    Wcomb[d * 64 + t * 8 + ee] = Wg[t * 8192 + d * 8 + ee];
  }
  if (d == 0) {
    float b0 = 0.f, b1 = 0.f, b2 = 0.f, b3 = 0.f;
#pragma unroll
    for (int j = 0; j < 8; ++j) {
      int h = lane + j * 64;
      float bv = be[e * 512 + h];
      b0 = fmaf(bv, Wt[h],        b0);
      b1 = fmaf(bv, Wt[512 + h],  b1);
      b2 = fmaf(bv, Wt[1024 + h], b2);
      b3 = fmaf(bv, Wt[1536 + h], b3);
    }
#pragma unroll
    for (int m = 1; m < 64; m <<= 1) {
      b0 += __shfl_xor(b0, m, 64); b1 += __shfl_xor(b1, m, 64);
      b2 += __shfl_xor(b2, m, 64); b3 += __shfl_xor(b3, m, 64);
    }
    if (lane == 0) {
      cbias[0 * 8 + e] = b0; cbias[1 * 8 + e] = b1;
      cbias[2 * 8 + e] = b2; cbias[3 * 8 + e] = b3;
    }
  }
}

// ---------------- Swizzle Wcomb -> bf16 hi/lo MFMA B-fragments (verified R2/R5/R7) ----------------
// Slot idx = ks*512 + vn*64 + lane; vn = v*4+nf (v:0=hi,1=lo). Lane l holds
// B[k = ks*32 + (l>>4)*8 + j][n = nf*16 + (l&15)], j=0..7, packed 2 bf16/u32.
__global__ __launch_bounds__(256) void mmoe_swizzle(const float* __restrict__ Wc,
                                                    uint4* __restrict__ wf)
{
  const int idx = blockIdx.x * 256 + threadIdx.x;  // 0..16383
  const int ks = idx >> 9;
  const int rem = idx & 511;
  const int vn = rem >> 6, l = rem & 63;
  const int v = vn >> 2, nf = vn & 3;
  const int n = nf * 16 + (l & 15);
  const int kbase = ks * 32 + (l >> 4) * 8;
  unsigned int pk[4];
#pragma unroll
  for (int p = 0; p < 4; ++p) {
    float f0 = Wc[(size_t)(kbase + 2 * p) * 64 + n];
    float f1 = Wc[(size_t)(kbase + 2 * p + 1) * 64 + n];
    unsigned int hi, lo;
    cvt_pair(f0, f1, hi, lo);
    pk[p] = v ? lo : hi;
  }
  uint4 val; val.x = pk[0]; val.y = pk[1]; val.z = pk[2]; val.w = pk[3];
  wf[idx] = val;
}

// ---------------- Main: 512 blocks x 4 waves; 32 rows/block, K-split 4 ----------------
// Wave w handles k in [w*256,(w+1)*256): 8 steps of K=32. sched_barrier(0) at each
// step boundary pins the 4-deep x / 2-deep B prefetch pipeline (R5 showed VGPR=72:
// compiler had sunk the prefetch loads to use sites, serializing on HBM latency).
union UC { unsigned int u[4]; bf16x8 v; };

template <int S>
__device__ __forceinline__ void mmoe_step(
    const float4* __restrict__ xp0, const float4* __restrict__ xp1,
    const bf16x8* __restrict__ bptrw, int l,
    float4 (&xbuf)[4][2][2], bf16x8 (&breg)[2][8], f32x4 (&acc)[2][4])
{
  constexpr int D = S & 3;   // xbuf depth slot
  constexpr int P = S & 1;   // breg parity
  float4 xa0 = xbuf[D][0][0], xa1 = xbuf[D][0][1];
  float4 xb0 = xbuf[D][1][0], xb1 = xbuf[D][1][1];
  if constexpr (S + 4 < 8) {
    xbuf[D][0][0] = xp0[(S + 4) * 8];
    xbuf[D][0][1] = xp0[(S + 4) * 8 + 1];
    xbuf[D][1][0] = xp1[(S + 4) * 8];
    xbuf[D][1][1] = xp1[(S + 4) * 8 + 1];
  }
  UC A0h, A0l, A1h, A1l;
  cvt_pair_fast(xa0.x, xa0.y, A0h.u[0], A0l.u[0]);
  cvt_pair_fast(xa0.z, xa0.w, A0h.u[1], A0l.u[1]);
  cvt_pair_fast(xa1.x, xa1.y, A0h.u[2], A0l.u[2]);
  cvt_pair_fast(xa1.z, xa1.w, A0h.u[3], A0l.u[3]);
  cvt_pair_fast(xb0.x, xb0.y, A1h.u[0], A1l.u[0]);
  cvt_pair_fast(xb0.z, xb0.w, A1h.u[1], A1l.u[1]);
  cvt_pair_fast(xb1.x, xb1.y, A1h.u[2], A1l.u[2]);
  cvt_pair_fast(xb1.z, xb1.w, A1h.u[3], A1l.u[3]);

  // bf16x3: Ah*Bh (j 0..3), Ah*Bl (j 4..7 are lo-B frags), Al*Bh
#pragma unroll
  for (int j = 0; j < 4; ++j)
    acc[0][j] = __builtin_amdgcn_mfma_f32_16x16x32_bf16(A0h.v, breg[P][j], acc[0][j], 0, 0, 0);
#pragma unroll
  for (int j = 0; j < 4; ++j)
    acc[1][j] = __builtin_amdgcn_mfma_f32_16x16x32_bf16(A1h.v, breg[P][j], acc[1][j], 0, 0, 0);
#pragma unroll
  for (int j = 0; j < 4; ++j)
    acc[0][j] = __builtin_amdgcn_mfma_f32_16x16x32_bf16(A0h.v, breg[P][j + 4], acc[0][j], 0, 0, 0);
#pragma unroll
  for (int j = 0; j < 4; ++j)
    acc[1][j] = __builtin_amdgcn_mfma_f32_16x16x32_bf16(A1h.v, breg[P][j + 4], acc[1][j], 0, 0, 0);
#pragma unroll
  for (int j = 0; j < 4; ++j)
    acc[0][j] = __builtin_amdgcn_mfma_f32_16x16x32_bf16(A0l.v, breg[P][j], acc[0][j], 0, 0, 0);
#pragma unroll
  for (int j = 0; j < 4; ++j)
    acc[1][j] = __builtin_amdgcn_mfma_f32_16x16x32_bf16(A1l.v, breg[P][j], acc[1][j], 0, 0, 0);
  if constexpr (S + 2 < 8) {
#pragma unroll
    for (int vn = 0; vn < 8; ++vn)
      breg[P][vn] = bptrw[(S + 2) * 512 + vn * 64 + l];
  }
  SCHED_FENCE();   // pin this step's prefetch issues here (no sinking across steps)
}

__global__ __launch_bounds__(256, 2) void mmoe_main(
    const float* __restrict__ x,
    const float* __restrict__ bgp,   // [4][8]
    const float* __restrict__ btp,   // [4]
    const float* __restrict__ ws,
    float* __restrict__ out)
{
  __shared__ float cmat[4 * 2048];   // [wave][32 rows][64 cols]
  const int tid = threadIdx.x;
  const int l   = tid & 63;
  const int w   = tid >> 6;          // K-quarter 0..3
  const int b0g = blockIdx.x * 32;
  const float* cbias = ws + 65536;
  const bf16x8* __restrict__ bptrw =
      (const bf16x8*)((const unsigned char*)ws + WFRAG_OFF_BYTES) + w * 8 * 512;

  // frag f covers rows b0g + f*16 + (l&15); lane k-octet (l>>4)*8 inside wave's K-quarter
  const float4* __restrict__ xp0 =
      (const float4*)(x + (size_t)(b0g + (l & 15)) * 1024) + w * 64 + (l >> 4) * 2;
  const float4* __restrict__ xp1 = xp0 + 16 * 256;   // +16 rows

  float4 xbuf[4][2][2];     // [depth][frag][vec]
  bf16x8 breg[2][8];
  f32x4  acc[2][4];
#pragma unroll
  for (int f = 0; f < 2; ++f)
#pragma unroll
    for (int nf = 0; nf < 4; ++nf) acc[f][nf] = (f32x4){0.f, 0.f, 0.f, 0.f};

  // prologue: x steps 0..3, B steps 0..1 — all issued before any compute, pinned
#pragma unroll
  for (int p = 0; p < 4; ++p) {
    xbuf[p][0][0] = xp0[p * 8]; xbuf[p][0][1] = xp0[p * 8 + 1];
    xbuf[p][1][0] = xp1[p * 8]; xbuf[p][1][1] = xp1[p * 8 + 1];
  }
#pragma unroll
  for (int vn = 0; vn < 8; ++vn) breg[0][vn] = bptrw[vn * 64 + l];
#pragma unroll
  for (int vn = 0; vn < 8; ++vn) breg[1][vn] = bptrw[512 + vn * 64 + l];
  SCHED_FENCE();

  mmoe_step<0>(xp0, xp1, bptrw, l, xbuf, breg, acc);
  mmoe_step<1>(xp0, xp1, bptrw, l, xbuf, breg, acc);
  mmoe_step<2>(xp0, xp1, bptrw, l, xbuf, breg, acc);
  mmoe_step<3>(xp0, xp1, bptrw, l, xbuf, breg, acc);
  mmoe_step<4>(xp0, xp1, bptrw, l, xbuf, breg, acc);
  mmoe_step<5>(xp0, xp1, bptrw, l, xbuf, breg, acc);
  mmoe_step<6>(xp0, xp1, bptrw, l, xbuf, breg, acc);
  mmoe_step<7>(xp0, xp1, bptrw, l, xbuf, breg, acc);

  // ---- write partials: C frag (col=lane&15, row=(lane>>4)*4+r) ----
#pragma unroll
  for (int f = 0; f < 2; ++f)
#pragma unroll
    for (int nf = 0; nf < 4; ++nf)
#pragma unroll
      for (int r = 0; r < 4; ++r)
        cmat[w * 2048 + (f * 16 + (l >> 4) * 4 + r) * 64 + nf * 16 + (l & 15)] = acc[f][nf][r];
  __syncthreads();

  // ---- 4-way reduce + softmax-mix (threads 0..127: 32 rows x 4 tasks) ----
  if (tid < 128) {
    const int row = tid >> 2, t = tid & 3;
    float g[8] = {0.f, 0.f, 0.f, 0.f, 0.f, 0.f, 0.f, 0.f};
    float s[8] = {0.f, 0.f, 0.f, 0.f, 0.f, 0.f, 0.f, 0.f};
#pragma unroll
    for (int wv = 0; wv < 4; ++wv) {
      const float4 ga = *(const float4*)&cmat[wv * 2048 + row * 64 + t * 8];
      const float4 gb = *(const float4*)&cmat[wv * 2048 + row * 64 + t * 8 + 4];
      const float4 sa = *(const float4*)&cmat[wv * 2048 + row * 64 + 32 + t * 8];
      const float4 sb = *(const float4*)&cmat[wv * 2048 + row * 64 + 32 + t * 8 + 4];
      g[0] += ga.x; g[1] += ga.y; g[2] += ga.z; g[3] += ga.w;
      g[4] += gb.x; g[5] += gb.y; g[6] += gb.z; g[7] += gb.w;
      s[0] += sa.x; s[1] += sa.y; s[2] += sa.z; s[3] += sa.w;
      s[4] += sb.x; s[5] += sb.y; s[6] += sb.z; s[7] += sb.w;
    }
#pragma unroll
    for (int e = 0; e < 8; ++e) {
      g[e] += bgp[t * 8 + e];
      s[e] += cbias[t * 8 + e];
    }
    float m = g[0];
#pragma unroll
    for (int e = 1; e < 8; ++e) m = fmaxf(m, g[e]);
    float Z = 0.f, num = 0.f;
#pragma unroll
    for (int e = 0; e < 8; ++e) {
      float p2 = __expf(g[e] - m);
      Z += p2;
      num = fmaf(p2, s[e], num);
    }
    out[t * 16384 + b0g + row] = num / Z + btp[t];
  }
}

extern "C" void kernel_launch(void* const* d_in, const int* in_sizes, int n_in,
                              void* d_out, int out_size, void* d_ws, size_t ws_size,
                              hipStream_t stream) {
  const float* x  = (const float*)d_in[0];
  const float* We = (const float*)d_in[1];
  const float* be = (const float*)d_in[2];
  const float* Wg = (const float*)d_in[3];
  const float* bg = (const float*)d_in[4];
  const float* Wt = (const float*)d_in[5];
  const float* bt = (const float*)d_in[6];
  float* out = (float*)d_out;
  float* ws  = (float*)d_ws;   // needs 524416 bytes

  uint4* wf = (uint4*)((unsigned char*)d_ws + WFRAG_OFF_BYTES);

  hipLaunchKernelGGL(mmoe_precompute, dim3(2048), dim3(256), 0, stream, We, be, Wg, Wt, ws);
  hipLaunchKernelGGL(mmoe_swizzle,    dim3(64),   dim3(256), 0, stream, ws, wf);
  hipLaunchKernelGGL(mmoe_main,       dim3(512),  dim3(256), 0, stream, x, bg, bt, ws, out);
}